// Round 11
// baseline (179.892 us; speedup 1.0000x reference)
//
#include <hip/hip_runtime.h>
#include <stdint.h>

typedef float v4f  __attribute__((ext_vector_type(4)));
typedef float v16f __attribute__((ext_vector_type(16)));
typedef short v8s  __attribute__((ext_vector_type(8)));
typedef uint32_t u32;

#define DEVI static __device__ __forceinline__

// fp32 -> bf16 (RNE), raw bits
DEVI unsigned short f2bf(float f) {
    u32 u = __builtin_bit_cast(u32, f);
    u = (u + 0x7fffu + ((u >> 16) & 1u)) >> 16;
    return (unsigned short)u;
}
DEVI float bf2f(unsigned short h) {
    u32 u = ((u32)h) << 16;
    return __builtin_bit_cast(float, u);
}

// async global->LDS, 16B per lane. HW dest = wave-uniform base + lane*16.
template <typename T>
DEVI void async16(const T* g, T* l) {
    __builtin_amdgcn_global_load_lds(
        (const __attribute__((address_space(1))) u32*)g,
        (__attribute__((address_space(3))) u32*)l, 16, 0, 0);
}

DEVI v4f bmfma(v8s a, v8s b, v4f c) {
    return __builtin_amdgcn_mfma_f32_16x16x32_bf16(a, b, c, 0, 0, 0);
}
DEVI v16f bmfma32(v8s a, v8s b, v16f c) {
    return __builtin_amdgcn_mfma_f32_32x32x16_bf16(a, b, c, 0, 0, 0);
}

#if __has_builtin(__builtin_amdgcn_permlane32_swap)
#define HAVE_PLSWAP 1
typedef unsigned int v2u __attribute__((ext_vector_type(2)));
#endif

// lo = [a.lanes0-31 | b.lanes0-31], hi = [a.lanes32-63 | b.lanes32-63]
DEVI void swap32(u32 a, u32 b, u32& lo, u32& hi) {
#ifdef HAVE_PLSWAP
    v2u r = __builtin_amdgcn_permlane32_swap(a, b, false, false);
    lo = r.x; hi = r.y;
#else
    u32 ax = __shfl_xor(a, 32), bx = __shfl_xor(b, 32);
    int hh = (threadIdx.x & 63) >> 5;
    lo = hh ? bx : a;
    hi = hh ? b : ax;
#endif
}

static const size_t HSZ = 32ull * 2048 * 64;  // per q/k/v region, elements

// ---------------------------------------------------------------------------
// prep_all: one launch for the 3 input-prep passes.
// fp32 [R][512] -> bf16, row sum-of-squares, optional row sum.
__launch_bounds__(256, 2)
__global__ void prep_all(const float* __restrict__ X, const float* __restrict__ WQ,
                         const float* __restrict__ WO,
                         unsigned short* __restrict__ Xb, unsigned short* __restrict__ WQb,
                         unsigned short* __restrict__ WOb,
                         float* __restrict__ xsq, float* __restrict__ wqsq,
                         float* __restrict__ wosq, float* __restrict__ wors)
{
    const int bid = blockIdx.x;
    const int w = threadIdx.x >> 6, lane = threadIdx.x & 63;
    const float* src; unsigned short* dst; float* Sq; float* Rs = nullptr;
    int r;
    if (bid < 2048)      { src = X;  dst = Xb;  Sq = xsq;  r = bid * 4 + w; }
    else if (bid < 2432) { src = WQ; dst = WQb; Sq = wqsq; r = (bid - 2048) * 4 + w; }
    else                 { src = WO; dst = WOb; Sq = wosq; Rs = wors; r = (bid - 2432) * 4 + w; }

    const float* xr = src + (size_t)r * 512 + lane * 8;
    float4 a = *(const float4*)xr;
    float4 c = *(const float4*)(xr + 4);
    float s = a.x*a.x + a.y*a.y + a.z*a.z + a.w*a.w
            + c.x*c.x + c.y*c.y + c.z*c.z + c.w*c.w;
    float sm = a.x + a.y + a.z + a.w + c.x + c.y + c.z + c.w;
    uint4 pkv;
    unsigned short* e = (unsigned short*)&pkv;
    e[0] = f2bf(a.x); e[1] = f2bf(a.y); e[2] = f2bf(a.z); e[3] = f2bf(a.w);
    e[4] = f2bf(c.x); e[5] = f2bf(c.y); e[6] = f2bf(c.z); e[7] = f2bf(c.w);
    *(uint4*)(dst + (size_t)r * 512 + lane * 8) = pkv;
#pragma unroll
    for (int d = 32; d > 0; d >>= 1) {
        s  += __shfl_xor(s, d);
        sm += __shfl_xor(sm, d);
    }
    if (lane == 0) { Sq[r] = s; if (Rs) Rs[r] = sm; }
}

// ---------------------------------------------------------------------------
// QKV cdist GEMM v2: 128x128 tile, 4 waves, 16x16x32 bf16 MFMA.
// Double-buffered LDS, BK=32, ONE barrier per K-step. LDS 32 KB.
//   tt=0 (q): *2*scale*log2e -> q'' region [bh][i][d]
//   tt=1 (k): -> k' region [bh][j][d]; fused ksqc[bh][j] = -sum_d k'^2 * CK
//   tt=2 (v): -> v' region TRANSPOSED [bh][d][j], via LDS-transpose epilogue
__launch_bounds__(256, 2)
__global__ void gemm_cdist(const unsigned short* __restrict__ A,
                           const unsigned short* __restrict__ B,
                           const float* __restrict__ Asq,
                           const float* __restrict__ Bsq,
                           unsigned short* __restrict__ QKV,
                           float* __restrict__ Ksqc)
{
    // [buf][mat][128*32] u16; 16384 u16 = 32 KB total. Reused as lT in epilogue.
    __shared__ unsigned short lsm[2 * 2 * 128 * 32];
    const int t = threadIdx.x;
    const int lane = t & 63, w = t >> 6;
    const int low = lane & 15, quad = lane >> 4;
    const int wm = w & 1, wn = w >> 1;
    const int tM = blockIdx.x * 128, tN = blockIdx.y * 128;

    v4f acc[4][4];
#pragma unroll
    for (int a = 0; a < 4; ++a)
#pragma unroll
        for (int b = 0; b < 4; ++b) acc[a][b] = (v4f){0.f, 0.f, 0.f, 0.f};

    int kstage = 0;
    auto STAGE = [&](int buf) {
        unsigned short* lA = lsm + buf * 8192;
        unsigned short* lB = lA + 4096;
#pragma unroll
        for (int is = 0; is < 2; ++is) {
            int slot = is * 256 + t;                 // 0..511
            int r = slot >> 2, bp = slot & 3, bs = bp ^ (r & 3);
            async16(A + (size_t)(tM + r) * 512 + kstage + bs * 8, lA + slot * 8);
            async16(B + (size_t)(tN + r) * 512 + kstage + bs * 8, lB + slot * 8);
        }
        kstage += 32;
    };

    STAGE(0);
    __syncthreads();   // prologue drain: k-tile 0 resident

#pragma unroll 2
    for (int iter = 0; iter < 16; ++iter) {
        const int c = iter & 1;
        if (iter < 15) STAGE(1 - c);   // overlaps compute below
        const unsigned short* lA = lsm + c * 8192;
        const unsigned short* lB = lA + 4096;

        v8s bfr[4];
#pragma unroll
        for (int ns = 0; ns < 4; ++ns) {
            int row = wn * 64 + ns * 16 + low;
            bfr[ns] = *(const v8s*)(lB + (row * 4 + (quad ^ (row & 3))) * 8);
        }
#pragma unroll
        for (int ms = 0; ms < 4; ++ms) {
            int row = wm * 64 + ms * 16 + low;
            v8s af = *(const v8s*)(lA + (row * 4 + (quad ^ (row & 3))) * 8);
#pragma unroll
            for (int ns = 0; ns < 4; ++ns)
                acc[ms][ns] = bmfma(af, bfr[ns], acc[ms][ns]);
        }
        __syncthreads();   // implicit vmcnt(0)+lgkmcnt(0): next buf ready,
                           // and this buf's readers done before next STAGE
    }

    const int tt = tN >> 9;  // block-uniform region id
    if (tt != 2) {
#pragma unroll
        for (int ms = 0; ms < 4; ++ms) {
#pragma unroll
            for (int reg = 0; reg < 4; ++reg) {
                const int row = tM + wm * 64 + ms * 16 + quad * 4 + reg;
                const int b = row >> 11, i = row & 2047;
                float kacc = 0.f;
#pragma unroll
                for (int ns = 0; ns < 4; ++ns) {
                    const int col = tN + wn * 64 + ns * 16 + low;
                    float dot = acc[ms][ns][reg];
                    float val = sqrtf(fmaxf(Asq[row] + Bsq[col] - 2.f * dot, 0.f)) - 32.f;
                    int h = (col >> 6) & 7, d = col & 63, bh = b * 8 + h;
                    if (tt == 0) {
                        QKV[((size_t)bh * 2048 + i) * 64 + d] =
                            f2bf(val * 0.36067376022224085f);  // 2*scale*log2e
                    } else {
                        QKV[HSZ + ((size_t)bh * 2048 + i) * 64 + d] = f2bf(val);
                        kacc += val * val;
                    }
                }
                if (tt == 1) {
#pragma unroll
                    for (int d = 1; d < 16; d <<= 1) kacc += __shfl_xor(kacc, d);
                    if (low == 0) {
                        int h = ((tN + wn * 64) >> 6) & 7;
                        // negated: serves as flash_attn's softmax C-init directly
                        Ksqc[(size_t)(b * 8 + h) * 2048 + i] = -kacc * 0.18033688011112042f;
                    }
                }
            }
        }
    } else {
        // v blocks: compute all vals, then 2-pass LDS transpose for coalesced
        // [bh][d][i] stores. lT: [col 0..127][row 0..63], stride 72 shorts.
        u32 packed[4][4][2];
#pragma unroll
        for (int ms = 0; ms < 4; ++ms)
#pragma unroll
            for (int ns = 0; ns < 4; ++ns) {
                const int col = tN + wn * 64 + ns * 16 + low;
                float bs_ = Bsq[col];
#pragma unroll
                for (int rp = 0; rp < 2; ++rp) {
                    u32 pk = 0;
#pragma unroll
                    for (int sub = 0; sub < 2; ++sub) {
                        int reg = rp * 2 + sub;
                        int row = tM + wm * 64 + ms * 16 + quad * 4 + reg;
                        float val = sqrtf(fmaxf(Asq[row] + bs_
                                                - 2.f * acc[ms][ns][reg], 0.f)) - 32.f;
                        pk |= (u32)f2bf(val) << (16 * sub);
                    }
                    packed[ms][ns][rp] = pk;
                }
            }
        u32* lT32 = (u32*)lsm;
#pragma unroll
        for (int p = 0; p < 2; ++p) {
            __syncthreads();
            if (wm == p) {
#pragma unroll
                for (int ms = 0; ms < 4; ++ms)
#pragma unroll
                    for (int ns = 0; ns < 4; ++ns) {
                        int cl = wn * 64 + ns * 16 + low;
#pragma unroll
                        for (int rp = 0; rp < 2; ++rp)
                            lT32[cl * 36 + ms * 8 + quad * 2 + rp] = packed[ms][ns][rp];
                    }
            }
            __syncthreads();
#pragma unroll
            for (int cc = 0; cc < 4; ++cc) {
                int col = cc * 32 + (t >> 3);
                int i0 = (t & 7) * 8;
                uint4 vvv = *(const uint4*)(lsm + col * 72 + i0);
                int colg = tN + col;
                int h = (colg >> 6) & 7, d = colg & 63;
                int rowg = tM + p * 64 + i0;
                int b = rowg >> 11, i = rowg & 2047;
                *(uint4*)(QKV + 2 * HSZ
                          + ((size_t)((b * 8 + h) * 64 + d)) * 2048 + i) = vvv;
            }
        }
    }
    (void)0;
}

// ---------------------------------------------------------------------------
// Flash attention v14 = v13 (split=1, dbuf, counted-vmcnt, XCD swizzle, ILP
// pairs) with ONE change: KVBLK 64 -> 128 (16 iters instead of 32).
// Round-5's KVBLK=128 failed because it ALSO dropped residency 4->2 blocks/CU;
// here residency is ALREADY 2 blocks/CU, so the bigger tile is free:
// LDS 40.5 -> 72 KB, 2x72=144 < 160 KB keeps 2 blocks/CU. Halves the per-iter
// fixed cost (2 barriers + drains + loop overhead) at identical DMA/MFMA/exp2.
// STAGE = 8 uniform DMA/thread -> counted wait becomes vmcnt(8).
// Epilogue: in-register normalize, final bf16 outp + osqp partials.
__launch_bounds__(256, 2)
__global__ void flash_attn(const unsigned short* __restrict__ Q,
                           const unsigned short* __restrict__ K,
                           const unsigned short* __restrict__ VT,
                           const float* __restrict__ Ksqc,
                           unsigned short* __restrict__ OP,
                           float* __restrict__ Osqp)
{
    __shared__ unsigned short lK[2][128 * 64];   // [j][d], XOR-8 swizzle, 8 slots/row
    __shared__ unsigned short lV[2][64 * 128];   // [d][j], XOR-8 swizzle, 16 slots/row
    __shared__ float lKqA[2048];                 // whole-bh -ksq*c, staged once
    const int t = threadIdx.x, lane = t & 63, w = t >> 6;
    const int i31 = lane & 31, h = lane >> 5;
    // XCD-aware decode of the 1D grid (T1)
    const int bid = blockIdx.x;
    const int bh = (bid & 7) * 4 + (bid >> 7);      // [0,32)
    const int qt = (bid >> 3) & 15;                 // [0,16)
    const size_t base = (size_t)bh * (2048 * 64);
    const int row0 = qt * 128 + w * 32;

    // Q fragments (B-operand layout): qfr[kt] = Q[row0+i31][16kt+8h..+7]
    v8s qfr[4];
#pragma unroll
    for (int kt = 0; kt < 4; ++kt)
        qfr[kt] = *(const v8s*)(Q + base + (size_t)(row0 + i31) * 64 + kt * 16 + h * 8);

    v16f o[2];
    float lacc = 0.f;
#pragma unroll
    for (int dt = 0; dt < 2; ++dt)
#pragma unroll
        for (int r = 0; r < 16; ++r) o[dt][r] = 0.f;

    const unsigned short* kg = K + base;
    const unsigned short* vg = VT + (size_t)bh * 64 * 2048;
    const float* kqg = Ksqc + (size_t)bh * 2048;

    auto STAGE = [&](int buf) {   // exactly 8 async16 per thread (uniform)
        // K tile: 128 rows x 64 u16 = 16 KB, 8 slots/row
#pragma unroll
        for (int is = 0; is < 4; ++is) {
            int slot = is * 256 + t;                 // 0..1023
            int r = slot >> 3, bp = slot & 7, bs = bp ^ (r & 7);
            async16(kg + (size_t)r * 64 + bs * 8, &lK[buf][slot * 8]);
        }
        // V tile: 64 rows x 128 u16 = 16 KB, 16 slots/row (XOR low 3 bits)
#pragma unroll
        for (int is = 0; is < 4; ++is) {
            int slot = is * 256 + t;                 // 0..1023
            int r = slot >> 4, bp = slot & 15, bs = bp ^ (r & 7);
            async16(vg + (size_t)r * 2048 + bs * 8, &lV[buf][slot * 8]);
        }
        kg += 128 * 64; vg += 128;
    };

    // prologue: whole-bh Ksqc (8 KB) + tile 0, then one full drain.
#pragma unroll
    for (int is = 0; is < 2; ++is) {
        int slot = is * 256 + t;
        async16(kqg + slot * 4, lKqA + slot * 4);
    }
    STAGE(0);
    __syncthreads();

#pragma unroll 2
    for (int iter = 0; iter < 16; ++iter) {
        const int c = iter & 1;

        // T4 counted-vmcnt sync
        asm volatile("s_waitcnt lgkmcnt(0)" ::: "memory");
        __builtin_amdgcn_s_barrier();            // buf^1 readers done
        if (iter < 15) {
            STAGE(1 - c);                        // prefetch: stays in flight
            asm volatile("s_waitcnt vmcnt(8)" ::: "memory");  // current buf in
        } else {
            asm volatile("s_waitcnt vmcnt(0)" ::: "memory");
        }
        __builtin_amdgcn_s_barrier();            // all waves' buf loads landed
        __builtin_amdgcn_sched_barrier(0);       // pin ds_reads below (rule 18)

        // 4 T-tiles of 32 j, processed as 2 ILP pairs (v13 ordering)
#pragma unroll
        for (int tp = 0; tp < 2; ++tp) {
            const int jrow0 = tp * 64 + i31, jrow1 = tp * 64 + 32 + i31;
            v8s kf0[4], kf1[4];
#pragma unroll
            for (int kt = 0; kt < 4; ++kt) {
                kf0[kt] = *(const v8s*)(&lK[c][(jrow0 * 8 + ((2 * kt + h) ^ (jrow0 & 7))) * 8]);
                kf1[kt] = *(const v8s*)(&lK[c][(jrow1 * 8 + ((2 * kt + h) ^ (jrow1 & 7))) * 8]);
            }
            v16f sa0, sa1;
#pragma unroll
            for (int r1 = 0; r1 < 4; ++r1) {
                v4f kq0 = *(const v4f*)(&lKqA[iter * 128 + tp * 64 + r1 * 8 + h * 4]);
                v4f kq1 = *(const v4f*)(&lKqA[iter * 128 + tp * 64 + 32 + r1 * 8 + h * 4]);
#pragma unroll
                for (int u = 0; u < 4; ++u) {
                    sa0[4 * r1 + u] = kq0[u];
                    sa1[4 * r1 + u] = kq1[u];
                }
            }
#pragma unroll
            for (int kt = 0; kt < 4; ++kt) sa0 = bmfma32(kf0[kt], qfr[kt], sa0);
#pragma unroll
            for (int kt = 0; kt < 4; ++kt) sa1 = bmfma32(kf1[kt], qfr[kt], sa1);

            // exp/pack(T0) + PV(T0): exp hides under QK(T1) MFMAs
            u32 pk0[8];
#pragma unroll
            for (int r1 = 0; r1 < 4; ++r1) {
                float p0 = exp2f(sa0[4 * r1 + 0]);
                float p1 = exp2f(sa0[4 * r1 + 1]);
                float p2 = exp2f(sa0[4 * r1 + 2]);
                float p3 = exp2f(sa0[4 * r1 + 3]);
                lacc += (p0 + p1) + (p2 + p3);
                pk0[2 * r1] = __builtin_amdgcn_perm(
                    __builtin_bit_cast(u32, p1), __builtin_bit_cast(u32, p0),
                    0x07060302u);
                pk0[2 * r1 + 1] = __builtin_amdgcn_perm(
                    __builtin_bit_cast(u32, p3), __builtin_bit_cast(u32, p2),
                    0x07060302u);
            }
#pragma unroll
            for (int c2 = 0; c2 < 2; ++c2) {
                const int jb = 2 * (2 * (2 * tp + 0) + c2);   // T = 2*tp
                v8s vf[2];
#pragma unroll
                for (int dt = 0; dt < 2; ++dt) {
                    const int drow = dt * 32 + i31;
                    vf[dt] = *(const v8s*)(&lV[c][(drow * 16 + ((jb + h) ^ (drow & 7))) * 8]);
                }
                uint4 dd;
                swap32(pk0[4 * c2 + 0], pk0[4 * c2 + 2], dd.x, dd.z);
                swap32(pk0[4 * c2 + 1], pk0[4 * c2 + 3], dd.y, dd.w);
                v8s af = __builtin_bit_cast(v8s, dd);
                o[0] = bmfma32(af, vf[0], o[0]);
                o[1] = bmfma32(af, vf[1], o[1]);
            }

            // exp/pack(T1) + PV(T1): exp hides under PV(T0) MFMAs
            u32 pk1[8];
#pragma unroll
            for (int r1 = 0; r1 < 4; ++r1) {
                float p0 = exp2f(sa1[4 * r1 + 0]);
                float p1 = exp2f(sa1[4 * r1 + 1]);
                float p2 = exp2f(sa1[4 * r1 + 2]);
                float p3 = exp2f(sa1[4 * r1 + 3]);
                lacc += (p0 + p1) + (p2 + p3);
                pk1[2 * r1] = __builtin_amdgcn_perm(
                    __builtin_bit_cast(u32, p1), __builtin_bit_cast(u32, p0),
                    0x07060302u);
                pk1[2 * r1 + 1] = __builtin_amdgcn_perm(
                    __builtin_bit_cast(u32, p3), __builtin_bit_cast(u32, p2),
                    0x07060302u);
            }
#pragma unroll
            for (int c2 = 0; c2 < 2; ++c2) {
                const int jb = 2 * (2 * (2 * tp + 1) + c2);   // T = 2*tp+1
                v8s vf[2];
#pragma unroll
                for (int dt = 0; dt < 2; ++dt) {
                    const int drow = dt * 32 + i31;
                    vf[dt] = *(const v8s*)(&lV[c][(drow * 16 + ((jb + h) ^ (drow & 7))) * 8]);
                }
                uint4 dd;
                swap32(pk1[4 * c2 + 0], pk1[4 * c2 + 2], dd.x, dd.z);
                swap32(pk1[4 * c2 + 1], pk1[4 * c2 + 3], dd.y, dd.w);
                v8s af = __builtin_bit_cast(v8s, dd);
                o[0] = bmfma32(af, vf[0], o[0]);
                o[1] = bmfma32(af, vf[1], o[1]);
            }
        }
    }

    // epilogue: normalize (l broadcast via shfl: C-layout row index is a lane
    // id), write final bf16 outp, emit per-head row-sq partials.
    const int b = bh >> 3, hh = bh & 7;
    lacc += __shfl_xor(lacc, 32);   // lanes now hold l for q-row row0+i31
    unsigned short* ob = OP + ((size_t)(b * 2048 + row0)) * 512 + hh * 64;
    float* osq = Osqp + (size_t)hh * 8192 + b * 2048 + row0;
#pragma unroll
    for (int r = 0; r < 16; ++r) {
        const int rl = (r & 3) + 8 * (r >> 2) + 4 * h;   // 0..31, row row0+rl
        float inv = 1.f / __shfl(lacc, rl);
        unsigned short e0 = f2bf(o[0][r] * inv);
        unsigned short e1 = f2bf(o[1][r] * inv);
        ob[(size_t)rl * 512 + i31] = e0;
        ob[(size_t)rl * 512 + 32 + i31] = e1;
        float f0 = bf2f(e0) + 32.f, f1 = bf2f(e1) + 32.f;
        float s = f0 * f0 + f1 * f1;
        s += __shfl_xor(s, 1);  s += __shfl_xor(s, 2);  s += __shfl_xor(s, 4);
        s += __shfl_xor(s, 8);  s += __shfl_xor(s, 16);
        if (i31 == 0) osq[rl] = s;
    }
}

// ---------------------------------------------------------------------------
// Output cdist GEMM v2: 128x64 tiles -> grid (64,8)=512 blocks.
// Double-buffered LDS (48 KB), ONE barrier per K-step.
// Asq = sum_h Osqp[h][row] (8 partials), staged once into LDS.
// val = sqrt(max(Asq+Bsq-2(dot+32*Brs),0)) -> fp32 OUT [8192][512].
__launch_bounds__(256, 2)
__global__ void gemm_out(const unsigned short* __restrict__ A,
                         const unsigned short* __restrict__ B,
                         const float* __restrict__ Osqp,
                         const float* __restrict__ Bsq,
                         const float* __restrict__ Brs,
                         float* __restrict__ OUT)
{
    __shared__ unsigned short lA[2][128 * 64];
    __shared__ unsigned short lB[2][64 * 64];
    __shared__ float lAsq[128];
    const int t = threadIdx.x;
    const int lane = t & 63, w = t >> 6;
    const int low = lane & 15, quad = lane >> 4;
    const int wm = w & 1, wn = w >> 1;
    const int tM = blockIdx.x * 128, tN = blockIdx.y * 64;

    if (t < 128) {
        float s = 0.f;
#pragma unroll
        for (int hh = 0; hh < 8; ++hh) s += Osqp[(size_t)hh * 8192 + tM + t];
        lAsq[t] = s;
    }

    v4f acc[4][2];
#pragma unroll
    for (int a = 0; a < 4; ++a)
#pragma unroll
        for (int b = 0; b < 2; ++b) acc[a][b] = (v4f){0.f, 0.f, 0.f, 0.f};

    int kstage = 0;
    auto STAGE = [&](int buf) {
#pragma unroll
        for (int is = 0; is < 4; ++is) {
            int slot = is * 256 + t;
            int r = slot >> 3, bp = slot & 7, bs = bp ^ (r & 7);
            async16(A + (size_t)(tM + r) * 512 + kstage + bs * 8, &lA[buf][slot * 8]);
        }
#pragma unroll
        for (int is = 0; is < 2; ++is) {
            int slot = is * 256 + t;
            int r = slot >> 3, bp = slot & 7, bs = bp ^ (r & 7);
            async16(B + (size_t)(tN + r) * 512 + kstage + bs * 8, &lB[buf][slot * 8]);
        }
        kstage += 64;
    };

    STAGE(0);
    __syncthreads();   // prologue drain: k-tile 0 resident (also covers lAsq)

#pragma unroll 2
    for (int iter = 0; iter < 8; ++iter) {
        const int c = iter & 1;
        if (iter < 7) STAGE(1 - c);   // overlaps compute below

        v8s bfr[2][2];
#pragma unroll
        for (int ns = 0; ns < 2; ++ns) {
            int row = wn * 32 + ns * 16 + low;
#pragma unroll
            for (int kc = 0; kc < 2; ++kc)
                bfr[ns][kc] = *(const v8s*)(&lB[c][(row * 8 + ((kc * 4 + quad) ^ (row & 7))) * 8]);
        }
#pragma unroll
        for (int ms = 0; ms < 4; ++ms) {
            int row = wm * 64 + ms * 16 + low;
            v8s af0 = *(const v8s*)(&lA[c][(row * 8 + ((0 + quad) ^ (row & 7))) * 8]);
            v8s af1 = *(const v8s*)(&lA[c][(row * 8 + ((4 + quad) ^ (row & 7))) * 8]);
#pragma unroll
            for (int ns = 0; ns < 2; ++ns) {
                acc[ms][ns] = bmfma(af0, bfr[ns][0], acc[ms][ns]);
                acc[ms][ns] = bmfma(af1, bfr[ns][1], acc[ms][ns]);
            }
        }
        __syncthreads();   // implicit drain; next buf ready before next STAGE
    }

#pragma unroll
    for (int ms = 0; ms < 4; ++ms) {
#pragma unroll
        for (int ns = 0; ns < 2; ++ns) {
#pragma unroll
            for (int reg = 0; reg < 4; ++reg) {
                int rloc = wm * 64 + ms * 16 + quad * 4 + reg;
                int row = tM + rloc;
                int col = tN + wn * 32 + ns * 16 + low;
                float val = sqrtf(fmaxf(lAsq[rloc] + Bsq[col]
                                        - 2.f * (acc[ms][ns][reg] + 32.f * Brs[col]), 0.f));
                OUT[(size_t)row * 512 + col] = val;
            }
        }
    }
}

// ---------------------------------------------------------------------------
extern "C" void kernel_launch(void* const* d_in, const int* in_sizes, int n_in,
                              void* d_out, int out_size, void* d_ws, size_t ws_size,
                              hipStream_t stream)
{
    const float* x    = (const float*)d_in[0];   // [4,2048,512]
    const float* wqkv = (const float*)d_in[1];   // [1536,512]
    const float* wout = (const float*)d_in[2];   // [512,512]
    float* out = (float*)d_out;                  // [4,2048,512] fp32

    char* ws = (char*)d_ws;
    size_t off = 0;
    auto alloc = [&](size_t bytes) -> void* {
        void* p = ws + off;
        off += (bytes + 255) & ~(size_t)255;
        return p;
    };
    unsigned short* xb   = (unsigned short*)alloc(8192ull * 512 * 2);
    unsigned short* wqb  = (unsigned short*)alloc(1536ull * 512 * 2);
    unsigned short* wob  = (unsigned short*)alloc(512ull * 512 * 2);
    unsigned short* qkv  = (unsigned short*)alloc(3ull * HSZ * 2);      // q'', k', v'^T
    unsigned short* outp = (unsigned short*)alloc(8192ull * 512 * 2);
    float* xsq  = (float*)alloc(8192 * 4);
    float* wqsq = (float*)alloc(1536 * 4);
    float* wosq = (float*)alloc(512 * 4);
    float* wors = (float*)alloc(512 * 4);
    float* ksqc = (float*)alloc(65536ull * 4);
    float* osqp = (float*)alloc(8ull * 8192 * 4);   // per-h row-sq partials

    prep_all<<<2560, 256, 0, stream>>>(x, wqkv, wout, xb, wqb, wob,
                                       xsq, wqsq, wosq, wors);

    gemm_cdist<<<dim3(64, 12), 256, 0, stream>>>(xb, wqb, xsq, wqsq, qkv, ksqc);
    flash_attn<<<512, 256, 0, stream>>>(qkv, qkv + HSZ, qkv + 2 * HSZ,
                                        ksqc, outp, osqp);
    gemm_out<<<dim3(64, 8), 256, 0, stream>>>(outp, wob, osqp, wosq, wors, out);
}

// Round 12
// 154.825 us; speedup vs baseline: 1.1619x; 1.1619x over previous
//
#include <hip/hip_runtime.h>
#include <stdint.h>

typedef float v4f  __attribute__((ext_vector_type(4)));
typedef float v16f __attribute__((ext_vector_type(16)));
typedef short v8s  __attribute__((ext_vector_type(8)));
typedef uint32_t u32;

#define DEVI static __device__ __forceinline__

// fp32 -> bf16 (RNE), raw bits
DEVI unsigned short f2bf(float f) {
    u32 u = __builtin_bit_cast(u32, f);
    u = (u + 0x7fffu + ((u >> 16) & 1u)) >> 16;
    return (unsigned short)u;
}
DEVI float bf2f(unsigned short h) {
    u32 u = ((u32)h) << 16;
    return __builtin_bit_cast(float, u);
}

// raw v_exp_f32: OCML exp2f without -ffast-math wraps the instruction in a
// ~5-op guarded range-fixup (only matters for |x|>~126). Our exponents are
// in-range (same no-max softmax passed 11 rounds); use the bare instruction.
DEVI float fexp2(float x) {
#if __has_builtin(__builtin_amdgcn_exp2f)
    return __builtin_amdgcn_exp2f(x);
#else
    float r;
    asm("v_exp_f32 %0, %1" : "=v"(r) : "v"(x));
    return r;
#endif
}

// async global->LDS, 16B per lane. HW dest = wave-uniform base + lane*16.
template <typename T>
DEVI void async16(const T* g, T* l) {
    __builtin_amdgcn_global_load_lds(
        (const __attribute__((address_space(1))) u32*)g,
        (__attribute__((address_space(3))) u32*)l, 16, 0, 0);
}

DEVI v4f bmfma(v8s a, v8s b, v4f c) {
    return __builtin_amdgcn_mfma_f32_16x16x32_bf16(a, b, c, 0, 0, 0);
}
DEVI v16f bmfma32(v8s a, v8s b, v16f c) {
    return __builtin_amdgcn_mfma_f32_32x32x16_bf16(a, b, c, 0, 0, 0);
}

#if __has_builtin(__builtin_amdgcn_permlane32_swap)
#define HAVE_PLSWAP 1
typedef unsigned int v2u __attribute__((ext_vector_type(2)));
#endif

// lo = [a.lanes0-31 | b.lanes0-31], hi = [a.lanes32-63 | b.lanes32-63]
DEVI void swap32(u32 a, u32 b, u32& lo, u32& hi) {
#ifdef HAVE_PLSWAP
    v2u r = __builtin_amdgcn_permlane32_swap(a, b, false, false);
    lo = r.x; hi = r.y;
#else
    u32 ax = __shfl_xor(a, 32), bx = __shfl_xor(b, 32);
    int hh = (threadIdx.x & 63) >> 5;
    lo = hh ? bx : a;
    hi = hh ? b : ax;
#endif
}

static const size_t HSZ = 32ull * 2048 * 64;  // per q/k/v region, elements

// ---------------------------------------------------------------------------
// prep_all: one launch for the 3 input-prep passes.
// fp32 [R][512] -> bf16, row sum-of-squares, optional row sum.
__launch_bounds__(256, 2)
__global__ void prep_all(const float* __restrict__ X, const float* __restrict__ WQ,
                         const float* __restrict__ WO,
                         unsigned short* __restrict__ Xb, unsigned short* __restrict__ WQb,
                         unsigned short* __restrict__ WOb,
                         float* __restrict__ xsq, float* __restrict__ wqsq,
                         float* __restrict__ wosq, float* __restrict__ wors)
{
    const int bid = blockIdx.x;
    const int w = threadIdx.x >> 6, lane = threadIdx.x & 63;
    const float* src; unsigned short* dst; float* Sq; float* Rs = nullptr;
    int r;
    if (bid < 2048)      { src = X;  dst = Xb;  Sq = xsq;  r = bid * 4 + w; }
    else if (bid < 2432) { src = WQ; dst = WQb; Sq = wqsq; r = (bid - 2048) * 4 + w; }
    else                 { src = WO; dst = WOb; Sq = wosq; Rs = wors; r = (bid - 2432) * 4 + w; }

    const float* xr = src + (size_t)r * 512 + lane * 8;
    float4 a = *(const float4*)xr;
    float4 c = *(const float4*)(xr + 4);
    float s = a.x*a.x + a.y*a.y + a.z*a.z + a.w*a.w
            + c.x*c.x + c.y*c.y + c.z*c.z + c.w*c.w;
    float sm = a.x + a.y + a.z + a.w + c.x + c.y + c.z + c.w;
    uint4 pkv;
    unsigned short* e = (unsigned short*)&pkv;
    e[0] = f2bf(a.x); e[1] = f2bf(a.y); e[2] = f2bf(a.z); e[3] = f2bf(a.w);
    e[4] = f2bf(c.x); e[5] = f2bf(c.y); e[6] = f2bf(c.z); e[7] = f2bf(c.w);
    *(uint4*)(dst + (size_t)r * 512 + lane * 8) = pkv;
#pragma unroll
    for (int d = 32; d > 0; d >>= 1) {
        s  += __shfl_xor(s, d);
        sm += __shfl_xor(sm, d);
    }
    if (lane == 0) { Sq[r] = s; if (Rs) Rs[r] = sm; }
}

// ---------------------------------------------------------------------------
// QKV cdist GEMM v2: 128x128 tile, 4 waves, 16x16x32 bf16 MFMA.
// Double-buffered LDS, BK=32, ONE barrier per K-step. LDS 32 KB.
//   tt=0 (q): *2*scale*log2e -> q'' region [bh][i][d]
//   tt=1 (k): -> k' region [bh][j][d]; fused ksqc[bh][j] = -sum_d k'^2 * CK
//   tt=2 (v): -> v' region TRANSPOSED [bh][d][j], via LDS-transpose epilogue
__launch_bounds__(256, 2)
__global__ void gemm_cdist(const unsigned short* __restrict__ A,
                           const unsigned short* __restrict__ B,
                           const float* __restrict__ Asq,
                           const float* __restrict__ Bsq,
                           unsigned short* __restrict__ QKV,
                           float* __restrict__ Ksqc)
{
    // [buf][mat][128*32] u16; 16384 u16 = 32 KB total. Reused as lT in epilogue.
    __shared__ unsigned short lsm[2 * 2 * 128 * 32];
    const int t = threadIdx.x;
    const int lane = t & 63, w = t >> 6;
    const int low = lane & 15, quad = lane >> 4;
    const int wm = w & 1, wn = w >> 1;
    const int tM = blockIdx.x * 128, tN = blockIdx.y * 128;

    v4f acc[4][4];
#pragma unroll
    for (int a = 0; a < 4; ++a)
#pragma unroll
        for (int b = 0; b < 4; ++b) acc[a][b] = (v4f){0.f, 0.f, 0.f, 0.f};

    int kstage = 0;
    auto STAGE = [&](int buf) {
        unsigned short* lA = lsm + buf * 8192;
        unsigned short* lB = lA + 4096;
#pragma unroll
        for (int is = 0; is < 2; ++is) {
            int slot = is * 256 + t;                 // 0..511
            int r = slot >> 2, bp = slot & 3, bs = bp ^ (r & 3);
            async16(A + (size_t)(tM + r) * 512 + kstage + bs * 8, lA + slot * 8);
            async16(B + (size_t)(tN + r) * 512 + kstage + bs * 8, lB + slot * 8);
        }
        kstage += 32;
    };

    STAGE(0);
    __syncthreads();   // prologue drain: k-tile 0 resident

#pragma unroll 2
    for (int iter = 0; iter < 16; ++iter) {
        const int c = iter & 1;
        if (iter < 15) STAGE(1 - c);   // overlaps compute below
        const unsigned short* lA = lsm + c * 8192;
        const unsigned short* lB = lA + 4096;

        v8s bfr[4];
#pragma unroll
        for (int ns = 0; ns < 4; ++ns) {
            int row = wn * 64 + ns * 16 + low;
            bfr[ns] = *(const v8s*)(lB + (row * 4 + (quad ^ (row & 3))) * 8);
        }
#pragma unroll
        for (int ms = 0; ms < 4; ++ms) {
            int row = wm * 64 + ms * 16 + low;
            v8s af = *(const v8s*)(lA + (row * 4 + (quad ^ (row & 3))) * 8);
#pragma unroll
            for (int ns = 0; ns < 4; ++ns)
                acc[ms][ns] = bmfma(af, bfr[ns], acc[ms][ns]);
        }
        __syncthreads();   // implicit vmcnt(0)+lgkmcnt(0): next buf ready,
                           // and this buf's readers done before next STAGE
    }

    const int tt = tN >> 9;  // block-uniform region id
    if (tt != 2) {
#pragma unroll
        for (int ms = 0; ms < 4; ++ms) {
#pragma unroll
            for (int reg = 0; reg < 4; ++reg) {
                const int row = tM + wm * 64 + ms * 16 + quad * 4 + reg;
                const int b = row >> 11, i = row & 2047;
                float kacc = 0.f;
#pragma unroll
                for (int ns = 0; ns < 4; ++ns) {
                    const int col = tN + wn * 64 + ns * 16 + low;
                    float dot = acc[ms][ns][reg];
                    float val = sqrtf(fmaxf(Asq[row] + Bsq[col] - 2.f * dot, 0.f)) - 32.f;
                    int h = (col >> 6) & 7, d = col & 63, bh = b * 8 + h;
                    if (tt == 0) {
                        QKV[((size_t)bh * 2048 + i) * 64 + d] =
                            f2bf(val * 0.36067376022224085f);  // 2*scale*log2e
                    } else {
                        QKV[HSZ + ((size_t)bh * 2048 + i) * 64 + d] = f2bf(val);
                        kacc += val * val;
                    }
                }
                if (tt == 1) {
#pragma unroll
                    for (int d = 1; d < 16; d <<= 1) kacc += __shfl_xor(kacc, d);
                    if (low == 0) {
                        int h = ((tN + wn * 64) >> 6) & 7;
                        // negated: serves as flash_attn's softmax C-init directly
                        Ksqc[(size_t)(b * 8 + h) * 2048 + i] = -kacc * 0.18033688011112042f;
                    }
                }
            }
        }
    } else {
        // v blocks: compute all vals, then 2-pass LDS transpose for coalesced
        // [bh][d][i] stores. lT: [col 0..127][row 0..63], stride 72 shorts.
        u32 packed[4][4][2];
#pragma unroll
        for (int ms = 0; ms < 4; ++ms)
#pragma unroll
            for (int ns = 0; ns < 4; ++ns) {
                const int col = tN + wn * 64 + ns * 16 + low;
                float bs_ = Bsq[col];
#pragma unroll
                for (int rp = 0; rp < 2; ++rp) {
                    u32 pk = 0;
#pragma unroll
                    for (int sub = 0; sub < 2; ++sub) {
                        int reg = rp * 2 + sub;
                        int row = tM + wm * 64 + ms * 16 + quad * 4 + reg;
                        float val = sqrtf(fmaxf(Asq[row] + bs_
                                                - 2.f * acc[ms][ns][reg], 0.f)) - 32.f;
                        pk |= (u32)f2bf(val) << (16 * sub);
                    }
                    packed[ms][ns][rp] = pk;
                }
            }
        u32* lT32 = (u32*)lsm;
#pragma unroll
        for (int p = 0; p < 2; ++p) {
            __syncthreads();
            if (wm == p) {
#pragma unroll
                for (int ms = 0; ms < 4; ++ms)
#pragma unroll
                    for (int ns = 0; ns < 4; ++ns) {
                        int cl = wn * 64 + ns * 16 + low;
#pragma unroll
                        for (int rp = 0; rp < 2; ++rp)
                            lT32[cl * 36 + ms * 8 + quad * 2 + rp] = packed[ms][ns][rp];
                    }
            }
            __syncthreads();
#pragma unroll
            for (int cc = 0; cc < 4; ++cc) {
                int col = cc * 32 + (t >> 3);
                int i0 = (t & 7) * 8;
                uint4 vvv = *(const uint4*)(lsm + col * 72 + i0);
                int colg = tN + col;
                int h = (colg >> 6) & 7, d = colg & 63;
                int rowg = tM + p * 64 + i0;
                int b = rowg >> 11, i = rowg & 2047;
                *(uint4*)(QKV + 2 * HSZ
                          + ((size_t)((b * 8 + h) * 64 + d)) * 2048 + i) = vvv;
            }
        }
    }
    (void)0;
}

// ---------------------------------------------------------------------------
// Flash attention v15 = v13 EXACTLY (split=1, KVBLK=64, dbuf, counted-vmcnt,
// XCD swizzle, ILP pairs — the 68us/169.6 best; v14's KVBLK=128 regressed and
// is reverted) + ONE change: exp2f -> raw v_exp_f32 (fexp2). OCML's exp2f
// without -ffast-math emits a ~5-op guarded range fixup per call; at 32
// calls/iter/wave on a 50%-VALUBusy kernel that's the largest removable VALU
// block. Numerically identical in-range.
// Epilogue: in-register normalize, final bf16 outp + osqp partials.
__launch_bounds__(256, 2)
__global__ void flash_attn(const unsigned short* __restrict__ Q,
                           const unsigned short* __restrict__ K,
                           const unsigned short* __restrict__ VT,
                           const float* __restrict__ Ksqc,
                           unsigned short* __restrict__ OP,
                           float* __restrict__ Osqp)
{
    __shared__ unsigned short lK[2][64 * 64];   // [j][d], XOR-8 swizzle
    __shared__ unsigned short lV[2][64 * 64];   // [d][j], XOR-8 swizzle
    __shared__ float lKqA[2048];                // whole-bh -ksq*c, staged once
    const int t = threadIdx.x, lane = t & 63, w = t >> 6;
    const int i31 = lane & 31, h = lane >> 5;
    // XCD-aware decode of the 1D grid (T1)
    const int bid = blockIdx.x;
    const int bh = (bid & 7) * 4 + (bid >> 7);      // [0,32)
    const int qt = (bid >> 3) & 15;                 // [0,16)
    const size_t base = (size_t)bh * (2048 * 64);
    const int row0 = qt * 128 + w * 32;

    // Q fragments (B-operand layout): qfr[kt] = Q[row0+i31][16kt+8h..+7]
    v8s qfr[4];
#pragma unroll
    for (int kt = 0; kt < 4; ++kt)
        qfr[kt] = *(const v8s*)(Q + base + (size_t)(row0 + i31) * 64 + kt * 16 + h * 8);

    v16f o[2];
    float lacc = 0.f;
#pragma unroll
    for (int dt = 0; dt < 2; ++dt)
#pragma unroll
        for (int r = 0; r < 16; ++r) o[dt][r] = 0.f;

    const unsigned short* kg = K + base;
    const unsigned short* vg = VT + (size_t)bh * 64 * 2048;
    const float* kqg = Ksqc + (size_t)bh * 2048;

    auto STAGE = [&](int buf) {   // exactly 4 async16 per thread (uniform)
#pragma unroll
        for (int is = 0; is < 2; ++is) {
            int slot = is * 256 + t;
            int r = slot >> 3, bp = slot & 7, bs = bp ^ (r & 7);
            async16(kg + (size_t)r * 64 + bs * 8, &lK[buf][slot * 8]);
        }
#pragma unroll
        for (int is = 0; is < 2; ++is) {
            int slot = is * 256 + t;
            int r = slot >> 3, bp = slot & 7, bs = bp ^ (r & 7);
            async16(vg + (size_t)r * 2048 + bs * 8, &lV[buf][slot * 8]);
        }
        kg += 64 * 64; vg += 64;
    };

    // prologue: whole-bh Ksqc (8 KB) + tile 0, then one full drain.
#pragma unroll
    for (int is = 0; is < 2; ++is) {
        int slot = is * 256 + t;
        async16(kqg + slot * 4, lKqA + slot * 4);
    }
    STAGE(0);
    __syncthreads();

#pragma unroll 2
    for (int iter = 0; iter < 32; ++iter) {
        const int c = iter & 1;

        // T4 counted-vmcnt sync
        asm volatile("s_waitcnt lgkmcnt(0)" ::: "memory");
        __builtin_amdgcn_s_barrier();            // buf^1 readers done
        if (iter < 31) {
            STAGE(1 - c);                        // prefetch: stays in flight
            asm volatile("s_waitcnt vmcnt(4)" ::: "memory");  // current buf in
        } else {
            asm volatile("s_waitcnt vmcnt(0)" ::: "memory");
        }
        __builtin_amdgcn_s_barrier();            // all waves' buf loads landed
        __builtin_amdgcn_sched_barrier(0);       // pin ds_reads below (rule 18)

        // ---- QK for BOTH 32-j halves first (independent MFMA streams) ----
        const int jrow0 = i31, jrow1 = 32 + i31;
        v8s kf0[4], kf1[4];
#pragma unroll
        for (int kt = 0; kt < 4; ++kt) {
            kf0[kt] = *(const v8s*)(&lK[c][(jrow0 * 8 + ((2 * kt + h) ^ (jrow0 & 7))) * 8]);
            kf1[kt] = *(const v8s*)(&lK[c][(jrow1 * 8 + ((2 * kt + h) ^ (jrow1 & 7))) * 8]);
        }
        v16f sa0, sa1;
#pragma unroll
        for (int r1 = 0; r1 < 4; ++r1) {
            v4f kq0 = *(const v4f*)(&lKqA[iter * 64 + r1 * 8 + h * 4]);
            v4f kq1 = *(const v4f*)(&lKqA[iter * 64 + 32 + r1 * 8 + h * 4]);
#pragma unroll
            for (int u = 0; u < 4; ++u) {
                sa0[4 * r1 + u] = kq0[u];
                sa1[4 * r1 + u] = kq1[u];
            }
        }
#pragma unroll
        for (int kt = 0; kt < 4; ++kt) sa0 = bmfma32(kf0[kt], qfr[kt], sa0);
#pragma unroll
        for (int kt = 0; kt < 4; ++kt) sa1 = bmfma32(kf1[kt], qfr[kt], sa1);

        // ---- exp/pack(T0) + PV(T0): exp(T0) hides under QK(T1) MFMAs ----
        u32 pk0[8];
#pragma unroll
        for (int r1 = 0; r1 < 4; ++r1) {
            float p0 = fexp2(sa0[4 * r1 + 0]);
            float p1 = fexp2(sa0[4 * r1 + 1]);
            float p2 = fexp2(sa0[4 * r1 + 2]);
            float p3 = fexp2(sa0[4 * r1 + 3]);
            lacc += (p0 + p1) + (p2 + p3);
            pk0[2 * r1] = __builtin_amdgcn_perm(
                __builtin_bit_cast(u32, p1), __builtin_bit_cast(u32, p0),
                0x07060302u);
            pk0[2 * r1 + 1] = __builtin_amdgcn_perm(
                __builtin_bit_cast(u32, p3), __builtin_bit_cast(u32, p2),
                0x07060302u);
        }
#pragma unroll
        for (int c2 = 0; c2 < 2; ++c2) {
            const int jb = 2 * c2;               // T=0: jb = 0, 2
            v8s vf[2];
#pragma unroll
            for (int dt = 0; dt < 2; ++dt) {
                const int drow = dt * 32 + i31;
                vf[dt] = *(const v8s*)(&lV[c][(drow * 8 + ((jb + h) ^ (drow & 7))) * 8]);
            }
            uint4 dd;
            swap32(pk0[4 * c2 + 0], pk0[4 * c2 + 2], dd.x, dd.z);
            swap32(pk0[4 * c2 + 1], pk0[4 * c2 + 3], dd.y, dd.w);
            v8s af = __builtin_bit_cast(v8s, dd);
            o[0] = bmfma32(af, vf[0], o[0]);
            o[1] = bmfma32(af, vf[1], o[1]);
        }

        // ---- exp/pack(T1) + PV(T1): exp(T1) hides under PV(T0) MFMAs ----
        u32 pk1[8];
#pragma unroll
        for (int r1 = 0; r1 < 4; ++r1) {
            float p0 = fexp2(sa1[4 * r1 + 0]);
            float p1 = fexp2(sa1[4 * r1 + 1]);
            float p2 = fexp2(sa1[4 * r1 + 2]);
            float p3 = fexp2(sa1[4 * r1 + 3]);
            lacc += (p0 + p1) + (p2 + p3);
            pk1[2 * r1] = __builtin_amdgcn_perm(
                __builtin_bit_cast(u32, p1), __builtin_bit_cast(u32, p0),
                0x07060302u);
            pk1[2 * r1 + 1] = __builtin_amdgcn_perm(
                __builtin_bit_cast(u32, p3), __builtin_bit_cast(u32, p2),
                0x07060302u);
        }
#pragma unroll
        for (int c2 = 0; c2 < 2; ++c2) {
            const int jb = 4 + 2 * c2;           // T=1: jb = 4, 6
            v8s vf[2];
#pragma unroll
            for (int dt = 0; dt < 2; ++dt) {
                const int drow = dt * 32 + i31;
                vf[dt] = *(const v8s*)(&lV[c][(drow * 8 + ((jb + h) ^ (drow & 7))) * 8]);
            }
            uint4 dd;
            swap32(pk1[4 * c2 + 0], pk1[4 * c2 + 2], dd.x, dd.z);
            swap32(pk1[4 * c2 + 1], pk1[4 * c2 + 3], dd.y, dd.w);
            v8s af = __builtin_bit_cast(v8s, dd);
            o[0] = bmfma32(af, vf[0], o[0]);
            o[1] = bmfma32(af, vf[1], o[1]);
        }
    }

    // epilogue: normalize (l broadcast via shfl: C-layout row index is a lane
    // id), write final bf16 outp, emit per-head row-sq partials.
    const int b = bh >> 3, hh = bh & 7;
    lacc += __shfl_xor(lacc, 32);   // lanes now hold l for q-row row0+i31
    unsigned short* ob = OP + ((size_t)(b * 2048 + row0)) * 512 + hh * 64;
    float* osq = Osqp + (size_t)hh * 8192 + b * 2048 + row0;
#pragma unroll
    for (int r = 0; r < 16; ++r) {
        const int rl = (r & 3) + 8 * (r >> 2) + 4 * h;   // 0..31, row row0+rl
        float inv = 1.f / __shfl(lacc, rl);
        unsigned short e0 = f2bf(o[0][r] * inv);
        unsigned short e1 = f2bf(o[1][r] * inv);
        ob[(size_t)rl * 512 + i31] = e0;
        ob[(size_t)rl * 512 + 32 + i31] = e1;
        float f0 = bf2f(e0) + 32.f, f1 = bf2f(e1) + 32.f;
        float s = f0 * f0 + f1 * f1;
        s += __shfl_xor(s, 1);  s += __shfl_xor(s, 2);  s += __shfl_xor(s, 4);
        s += __shfl_xor(s, 8);  s += __shfl_xor(s, 16);
        if (i31 == 0) osq[rl] = s;
    }
}

// ---------------------------------------------------------------------------
// Output cdist GEMM v2: 128x64 tiles -> grid (64,8)=512 blocks.
// Double-buffered LDS (48 KB), ONE barrier per K-step.
// Asq = sum_h Osqp[h][row] (8 partials), staged once into LDS.
// val = sqrt(max(Asq+Bsq-2(dot+32*Brs),0)) -> fp32 OUT [8192][512].
__launch_bounds__(256, 2)
__global__ void gemm_out(const unsigned short* __restrict__ A,
                         const unsigned short* __restrict__ B,
                         const float* __restrict__ Osqp,
                         const float* __restrict__ Bsq,
                         const float* __restrict__ Brs,
                         float* __restrict__ OUT)
{
    __shared__ unsigned short lA[2][128 * 64];
    __shared__ unsigned short lB[2][64 * 64];
    __shared__ float lAsq[128];
    const int t = threadIdx.x;
    const int lane = t & 63, w = t >> 6;
    const int low = lane & 15, quad = lane >> 4;
    const int wm = w & 1, wn = w >> 1;
    const int tM = blockIdx.x * 128, tN = blockIdx.y * 64;

    if (t < 128) {
        float s = 0.f;
#pragma unroll
        for (int hh = 0; hh < 8; ++hh) s += Osqp[(size_t)hh * 8192 + tM + t];
        lAsq[t] = s;
    }

    v4f acc[4][2];
#pragma unroll
    for (int a = 0; a < 4; ++a)
#pragma unroll
        for (int b = 0; b < 2; ++b) acc[a][b] = (v4f){0.f, 0.f, 0.f, 0.f};

    int kstage = 0;
    auto STAGE = [&](int buf) {
#pragma unroll
        for (int is = 0; is < 4; ++is) {
            int slot = is * 256 + t;
            int r = slot >> 3, bp = slot & 7, bs = bp ^ (r & 7);
            async16(A + (size_t)(tM + r) * 512 + kstage + bs * 8, &lA[buf][slot * 8]);
        }
#pragma unroll
        for (int is = 0; is < 2; ++is) {
            int slot = is * 256 + t;
            int r = slot >> 3, bp = slot & 7, bs = bp ^ (r & 7);
            async16(B + (size_t)(tN + r) * 512 + kstage + bs * 8, &lB[buf][slot * 8]);
        }
        kstage += 64;
    };

    STAGE(0);
    __syncthreads();   // prologue drain: k-tile 0 resident (also covers lAsq)

#pragma unroll 2
    for (int iter = 0; iter < 8; ++iter) {
        const int c = iter & 1;
        if (iter < 7) STAGE(1 - c);   // overlaps compute below

        v8s bfr[2][2];
#pragma unroll
        for (int ns = 0; ns < 2; ++ns) {
            int row = wn * 32 + ns * 16 + low;
#pragma unroll
            for (int kc = 0; kc < 2; ++kc)
                bfr[ns][kc] = *(const v8s*)(&lB[c][(row * 8 + ((kc * 4 + quad) ^ (row & 7))) * 8]);
        }
#pragma unroll
        for (int ms = 0; ms < 4; ++ms) {
            int row = wm * 64 + ms * 16 + low;
            v8s af0 = *(const v8s*)(&lA[c][(row * 8 + ((0 + quad) ^ (row & 7))) * 8]);
            v8s af1 = *(const v8s*)(&lA[c][(row * 8 + ((4 + quad) ^ (row & 7))) * 8]);
#pragma unroll
            for (int ns = 0; ns < 2; ++ns) {
                acc[ms][ns] = bmfma(af0, bfr[ns][0], acc[ms][ns]);
                acc[ms][ns] = bmfma(af1, bfr[ns][1], acc[ms][ns]);
            }
        }
        __syncthreads();   // implicit drain; next buf ready before next STAGE
    }

#pragma unroll
    for (int ms = 0; ms < 4; ++ms) {
#pragma unroll
        for (int ns = 0; ns < 2; ++ns) {
#pragma unroll
            for (int reg = 0; reg < 4; ++reg) {
                int rloc = wm * 64 + ms * 16 + quad * 4 + reg;
                int row = tM + rloc;
                int col = tN + wn * 32 + ns * 16 + low;
                float val = sqrtf(fmaxf(lAsq[rloc] + Bsq[col]
                                        - 2.f * (acc[ms][ns][reg] + 32.f * Brs[col]), 0.f));
                OUT[(size_t)row * 512 + col] = val;
            }
        }
    }
}

// ---------------------------------------------------------------------------
extern "C" void kernel_launch(void* const* d_in, const int* in_sizes, int n_in,
                              void* d_out, int out_size, void* d_ws, size_t ws_size,
                              hipStream_t stream)
{
    const float* x    = (const float*)d_in[0];   // [4,2048,512]
    const float* wqkv = (const float*)d_in[1];   // [1536,512]
    const float* wout = (const float*)d_in[2];   // [512,512]
    float* out = (float*)d_out;                  // [4,2048,512] fp32

    char* ws = (char*)d_ws;
    size_t off = 0;
    auto alloc = [&](size_t bytes) -> void* {
        void* p = ws + off;
        off += (bytes + 255) & ~(size_t)255;
        return p;
    };
    unsigned short* xb   = (unsigned short*)alloc(8192ull * 512 * 2);
    unsigned short* wqb  = (unsigned short*)alloc(1536ull * 512 * 2);
    unsigned short* wob  = (unsigned short*)alloc(512ull * 512 * 2);
    unsigned short* qkv  = (unsigned short*)alloc(3ull * HSZ * 2);      // q'', k', v'^T
    unsigned short* outp = (unsigned short*)alloc(8192ull * 512 * 2);
    float* xsq  = (float*)alloc(8192 * 4);
    float* wqsq = (float*)alloc(1536 * 4);
    float* wosq = (float*)alloc(512 * 4);
    float* wors = (float*)alloc(512 * 4);
    float* ksqc = (float*)alloc(65536ull * 4);
    float* osqp = (float*)alloc(8ull * 8192 * 4);   // per-h row-sq partials

    prep_all<<<2560, 256, 0, stream>>>(x, wqkv, wout, xb, wqb, wob,
                                       xsq, wqsq, wosq, wors);

    gemm_cdist<<<dim3(64, 12), 256, 0, stream>>>(xb, wqb, xsq, wqsq, qkv, ksqc);
    flash_attn<<<512, 256, 0, stream>>>(qkv, qkv + HSZ, qkv + 2 * HSZ,
                                        ksqc, outp, osqp);
    gemm_out<<<dim3(64, 8), 256, 0, stream>>>(outp, wob, osqp, wosq, wors, out);
}